// Round 1
// baseline (9105.517 us; speedup 1.0000x reference)
//
#include <hip/hip_runtime.h>
#include <math.h>

#define BB 32          // batch
#define TT 128         // time steps
#define EE 512         // embed dim
#define HH 1024        // hidden
#define VV 32000       // vocab
#define GG (4*HH)      // 4096 gates
#define MBT (BB*TT)    // 4096 rows
#define NS 16          // K-split slices for recurrent GEMM

// ---------------------------------------------------------------------------
// Generic NT SGEMM: C[m][n] = sum_k A[row(m)][k] * Bw[n][k] + bias0[n] + bias1[n]
// Block tile 128x128, BK=16, 256 threads, 8x8 per-thread register tile.
// GATHER: A row index comes from rows[m] (embedding lookup fusion).
// ---------------------------------------------------------------------------
template<bool GATHER>
__global__ __launch_bounds__(256)
void sgemm_nt(const float* __restrict__ A, const float* __restrict__ Bw,
              float* __restrict__ C,
              const int* __restrict__ rows,
              const float* __restrict__ bias0, const float* __restrict__ bias1,
              int M, int N, int K)
{
    // +4 pad keeps 16B alignment for float4 LDS reads and breaks bank patterns
    __shared__ float As[16][132];
    __shared__ float Bs[16][132];

    const int tid = threadIdx.x;
    const int tx = tid & 15;       // n-dim: 16 threads * 8 cols = 128
    const int ty = tid >> 4;       // m-dim: 16 threads * 8 rows = 128
    const int bm = blockIdx.y * 128;
    const int bn = blockIdx.x * 128;

    // staging: 2 threads per tile-row, each loads 8 contiguous k (2x float4)
    const int sr = tid & 127;        // row within 128-row tile
    const int sq = (tid >> 7) * 8;   // k offset: 0 or 8

    const float* aBase;
    if (GATHER) aBase = A + (size_t)rows[bm + sr] * K;
    else        aBase = A + (size_t)(bm + sr) * K;
    const float* bBase = Bw + (size_t)(bn + sr) * K;

    float acc[8][8];
#pragma unroll
    for (int i = 0; i < 8; ++i)
#pragma unroll
        for (int j = 0; j < 8; ++j) acc[i][j] = 0.f;

    for (int k0 = 0; k0 < K; k0 += 16) {
        float4 av0 = *(const float4*)(aBase + k0 + sq);
        float4 av1 = *(const float4*)(aBase + k0 + sq + 4);
        float4 bv0 = *(const float4*)(bBase + k0 + sq);
        float4 bv1 = *(const float4*)(bBase + k0 + sq + 4);

        __syncthreads();   // previous compute pass done before overwrite
        As[sq+0][sr] = av0.x; As[sq+1][sr] = av0.y;
        As[sq+2][sr] = av0.z; As[sq+3][sr] = av0.w;
        As[sq+4][sr] = av1.x; As[sq+5][sr] = av1.y;
        As[sq+6][sr] = av1.z; As[sq+7][sr] = av1.w;
        Bs[sq+0][sr] = bv0.x; Bs[sq+1][sr] = bv0.y;
        Bs[sq+2][sr] = bv0.z; Bs[sq+3][sr] = bv0.w;
        Bs[sq+4][sr] = bv1.x; Bs[sq+5][sr] = bv1.y;
        Bs[sq+6][sr] = bv1.z; Bs[sq+7][sr] = bv1.w;
        __syncthreads();

#pragma unroll
        for (int k = 0; k < 16; ++k) {
            float a[8], b[8];
            *(float4*)&a[0] = *(const float4*)&As[k][ty*8];
            *(float4*)&a[4] = *(const float4*)&As[k][ty*8 + 4];
            *(float4*)&b[0] = *(const float4*)&Bs[k][tx*8];
            *(float4*)&b[4] = *(const float4*)&Bs[k][tx*8 + 4];
#pragma unroll
            for (int i = 0; i < 8; ++i)
#pragma unroll
                for (int j = 0; j < 8; ++j)
                    acc[i][j] = fmaf(a[i], b[j], acc[i][j]);
        }
    }

    float bz[8];
#pragma unroll
    for (int j = 0; j < 8; ++j) {
        float bb = 0.f;
        if (bias0) bb += bias0[bn + tx*8 + j];
        if (bias1) bb += bias1[bn + tx*8 + j];
        bz[j] = bb;
    }
#pragma unroll
    for (int i = 0; i < 8; ++i) {
        float* cp = C + (size_t)(bm + ty*8 + i) * N + bn + tx*8;
        float4 o0, o1;
        o0.x = acc[i][0] + bz[0]; o0.y = acc[i][1] + bz[1];
        o0.z = acc[i][2] + bz[2]; o0.w = acc[i][3] + bz[3];
        o1.x = acc[i][4] + bz[4]; o1.y = acc[i][5] + bz[5];
        o1.z = acc[i][6] + bz[6]; o1.w = acc[i][7] + bz[7];
        *(float4*)cp = o0;
        *(float4*)(cp + 4) = o1;
    }
}

// ---------------------------------------------------------------------------
// Transpose W_hh [G][H] -> Wt [H][G] so recurrent GEMM loads coalesce over g.
// ---------------------------------------------------------------------------
__global__ __launch_bounds__(256)
void transpose_whh(const float* __restrict__ W, float* __restrict__ Wt)
{
    __shared__ float tile[32][33];
    const int bx = blockIdx.x * 32;  // along H (k)
    const int by = blockIdx.y * 32;  // along G (g)
    const int x = threadIdx.x;       // 32
    const int y = threadIdx.y;       // 8
#pragma unroll
    for (int i = 0; i < 32; i += 8)
        tile[y + i][x] = W[(size_t)(by + y + i) * HH + bx + x];
    __syncthreads();
#pragma unroll
    for (int i = 0; i < 32; i += 8)
        Wt[(size_t)(bx + y + i) * GG + by + x] = tile[x][y + i];
}

// ---------------------------------------------------------------------------
// Recurrent partial GEMM: part[s][b][g] = sum_{k in slice s} h[b][k] * Wt[k][g]
// grid (G/256, NS), 256 threads. h reads are wave-uniform -> scalar loads.
// ---------------------------------------------------------------------------
__global__ __launch_bounds__(256)
void lstm_partial(const float* __restrict__ Wt, const float* __restrict__ h,
                  float* __restrict__ part)
{
    const int g  = blockIdx.x * 256 + threadIdx.x;
    const int k0 = blockIdx.y * (HH / NS);   // 64-wide k slice

    float acc[BB];
#pragma unroll
    for (int b = 0; b < BB; ++b) acc[b] = 0.f;

    for (int kk = 0; kk < HH / NS; kk += 4) {
        const float w0 = Wt[(size_t)(k0 + kk + 0) * GG + g];
        const float w1 = Wt[(size_t)(k0 + kk + 1) * GG + g];
        const float w2 = Wt[(size_t)(k0 + kk + 2) * GG + g];
        const float w3 = Wt[(size_t)(k0 + kk + 3) * GG + g];
#pragma unroll
        for (int b = 0; b < BB; ++b) {
            float4 hv = *(const float4*)&h[b * HH + k0 + kk];  // uniform
            float a = acc[b];
            a = fmaf(hv.x, w0, a);
            a = fmaf(hv.y, w1, a);
            a = fmaf(hv.z, w2, a);
            a = fmaf(hv.w, w3, a);
            acc[b] = a;
        }
    }
#pragma unroll
    for (int b = 0; b < BB; ++b)
        part[((size_t)blockIdx.y * BB + b) * GG + g] = acc[b];
}

// ---------------------------------------------------------------------------
// Reduce partials + gate nonlinearities + state update + write hs row.
// One thread per (b, hidden) cell. PyTorch gate order: i, f, g, o.
// ---------------------------------------------------------------------------
__global__ __launch_bounds__(256)
void lstm_cell(const float* __restrict__ xg, const float* __restrict__ part,
               float* __restrict__ hbuf, float* __restrict__ cbuf,
               float* __restrict__ hs, int t)
{
    const int id = blockIdx.x * 256 + threadIdx.x;  // 0..B*H-1
    const int b  = id >> 10;
    const int hh = id & (HH - 1);
    const int m  = b * TT + t;

    float gv[4];
#pragma unroll
    for (int gate = 0; gate < 4; ++gate) {
        const int base = gate * HH + hh;
        float v = xg[(size_t)m * GG + base];
#pragma unroll
        for (int s = 0; s < NS; ++s)
            v += part[((size_t)s * BB + b) * GG + base];
        gv[gate] = v;
    }

    const float ig = 1.f / (1.f + expf(-gv[0]));
    const float fg = 1.f / (1.f + expf(-gv[1]));
    const float gg = tanhf(gv[2]);
    const float og = 1.f / (1.f + expf(-gv[3]));

    const float c = fg * cbuf[id] + ig * gg;
    const float hn = og * tanhf(c);
    cbuf[id] = c;
    hbuf[id] = hn;
    hs[(size_t)m * HH + hh] = hn;
}

// ---------------------------------------------------------------------------
extern "C" void kernel_launch(void* const* d_in, const int* in_sizes, int n_in,
                              void* d_out, int out_size, void* d_ws, size_t ws_size,
                              hipStream_t stream)
{
    const int*   x     = (const int*)d_in[0];
    const float* embed = (const float*)d_in[1];
    const float* W_ih  = (const float*)d_in[2];
    const float* W_hh  = (const float*)d_in[3];
    const float* b_ih  = (const float*)d_in[4];
    const float* b_hh  = (const float*)d_in[5];
    const float* fc_w  = (const float*)d_in[6];
    const float* fc_b  = (const float*)d_in[7];
    float* out = (float*)d_out;

    char* ws = (char*)d_ws;
    float* xg   = (float*)ws;  ws += (size_t)MBT * GG * 4;   // 64 MB
    float* Wt   = (float*)ws;  ws += (size_t)HH * GG * 4;    // 16.8 MB
    float* hs   = (float*)ws;  ws += (size_t)MBT * HH * 4;   // 16.8 MB
    float* part = (float*)ws;  ws += (size_t)NS * BB * GG * 4; // 8.4 MB
    float* hbuf = (float*)ws;  ws += (size_t)BB * HH * 4;    // 128 KB
    float* cbuf = (float*)ws;  ws += (size_t)BB * HH * 4;    // 128 KB

    // h0 = c0 = 0 (hbuf and cbuf are contiguous)
    hipMemsetAsync(hbuf, 0, (size_t)BB * HH * 4 * 2, stream);

    // W_hh transpose for coalesced recurrent loads
    transpose_whh<<<dim3(HH / 32, GG / 32), dim3(32, 8), 0, stream>>>(W_hh, Wt);

    // xg = embed[x] @ W_ih^T + b_ih + b_hh   (gather fused into A staging)
    sgemm_nt<true><<<dim3(GG / 128, MBT / 128), 256, 0, stream>>>(
        embed, W_ih, xg, x, b_ih, b_hh, MBT, GG, EE);

    // sequential LSTM scan
    for (int t = 0; t < TT; ++t) {
        lstm_partial<<<dim3(GG / 256, NS), 256, 0, stream>>>(Wt, hbuf, part);
        lstm_cell<<<dim3(BB * HH / 256), 256, 0, stream>>>(xg, part, hbuf, cbuf, hs, t);
    }

    // out = hs @ fc_w^T + fc_b   (268 GFLOP — the dominant cost)
    sgemm_nt<false><<<dim3(VV / 128, MBT / 128), 256, 0, stream>>>(
        hs, fc_w, out, nullptr, fc_b, nullptr, MBT, VV, HH);
}